// Round 7
// baseline (339.450 us; speedup 1.0000x reference)
//
#include <hip/hip_runtime.h>
#include <hip/hip_fp16.h>

#define BATCH 65536
#define KDIM  784
#define HID   512
#define BM    32

typedef float    f32x4 __attribute__((ext_vector_type(4)));
typedef _Float16 f16x8 __attribute__((ext_vector_type(8)));
typedef _Float16 f16x4 __attribute__((ext_vector_type(4)));

__device__ __forceinline__ void gload_lds16(const void* g, void* l) {
  __builtin_amdgcn_global_load_lds((const __attribute__((address_space(1))) void*)g,
                                   (__attribute__((address_space(3))) void*)l, 16, 0, 0);
}

// W1 (784x512 fp32) -> ws: fp16 in exact A-fragment order [net][kt][hid][32],
// zero-padded to k=800. Consumed global(L2)->reg.
__global__ void prep_w1_kernel(const float* __restrict__ W1_0,
                               const float* __restrict__ W1_1,
                               _Float16* __restrict__ wsB) {
  int i = blockIdx.x * 256 + threadIdx.x;       // [0, 2*800*512)
  if (i >= 2 * 800 * 512) return;
  int net = i / (800 * 512);
  int rem = i - net * (800 * 512);
  int k = rem >> 9;        // 0..799
  int hid = rem & 511;
  const float* W = net ? W1_1 : W1_0;
  float v = (k < KDIM) ? W[k * 512 + hid] : 0.f;
  int kt = k >> 5, kk = k & 31;
  wsB[(((size_t)(net * 25 + kt) * HID + hid) << 5) + kk] = (_Float16)v;
}

// W2 (512x10 fp32) -> ws: fp16 W2^T padded to 16 rows, [net][16][512], linear.
__global__ void prep_w2_kernel(const float* __restrict__ W2_0,
                               const float* __restrict__ W2_1,
                               _Float16* __restrict__ wsW2) {
  int i = blockIdx.x * 256 + threadIdx.x;       // [0, 2*16*512)
  if (i >= 2 * 16 * 512) return;
  int net = i >> 13;
  int rem = i & 8191;
  int li = rem >> 9;       // logit row 0..15
  int k = rem & 511;
  const float* W = net ? W2_1 : W2_0;
  wsW2[i] = (_Float16)((li < 10) ? W[k * 10 + li] : 0.f);
}

__launch_bounds__(256, 3)
__global__ void fused_mlp_kernel(const float* __restrict__ x,
                                 const float* __restrict__ b1_0,
                                 const float* __restrict__ b2_0,
                                 const float* __restrict__ b1_1,
                                 const float* __restrict__ b2_1,
                                 const _Float16* __restrict__ wsB,
                                 const _Float16* __restrict__ wsW2,
                                 float* __restrict__ out) {
  // bufA/bufB: x k=128 chunks (32 rows x 512B, linear dest / source-swizzled),
  // then h overlay (rows 0..15 -> bufA, 16..31 -> bufB, 1KB/row), then outb in bufA.
  __shared__ __attribute__((aligned(16))) char bufA[16384];
  __shared__ __attribute__((aligned(16))) char bufB[16384];
  __shared__ float pbuf[2][BM * 11];

  const int t    = threadIdx.x;
  const int lane = t & 63;
  const int wid  = t >> 6;            // 0..3
  const int l15  = lane & 15;
  const int l4   = lane >> 4;
  const int hid0 = wid << 7;          // wave owns hid [hid0, hid0+128)
  const int row0 = blockIdx.x * BM;

  for (int net = 0; net < 2; ++net) {
    const float* xb = x + (size_t)net * BATCH * KDIM + (size_t)row0 * KDIM;
    const _Float16* wnet = wsB + (size_t)net * 25 * HID * 32;
    const float* b1 = net ? b1_1 : b1_0;
    const float* b2 = net ? b2_1 : b2_0;

    f32x4 acc[8][2];
#pragma unroll
    for (int rf = 0; rf < 8; ++rf)
#pragma unroll
      for (int nf = 0; nf < 2; ++nf) acc[rf][nf] = (f32x4){0.f, 0.f, 0.f, 0.f};

    // stage one k=128 chunk (16KB): LDS[r][s] = x[r][k0 + (s^(r&7))*4 ..+3]
    auto stage_chunk = [&](const float* src, char* buf) {
#pragma unroll
      for (int i = 0; i < 4; ++i) {
        int cu = (wid << 2) + i;          // 1KB unit 0..15
        int r  = (cu << 1) + (lane >> 5); // row 0..31
        int g  = (lane & 31) ^ (r & 7);   // source 16B slot
        gload_lds16(src + (size_t)r * KDIM + (g << 2), buf + (cu << 10));
      }
    };
    // tail (kt 24, k 768..799): 4KB into bufA; slots>=4 clamp to garbage (W1 zero-padded)
    auto stage_tail = [&]() {
      int cu = wid;                       // 1KB unit 0..3
      int r  = (cu << 3) + (lane >> 3);   // row 0..31
      int g  = (lane & 7) ^ (r & 7);
      int ge = (g < 4) ? (768 + (g << 2)) : 0;
      gload_lds16(xb + (size_t)r * KDIM + ge, bufA + (cu << 10));
    };
    // compute the 4 K-tiles of a chunk (W1 frags from L2 -> reg; x from LDS)
    auto compute_chunk = [&](const char* xl, int kt0) {
#pragma unroll 2
      for (int ktl = 0; ktl < 4; ++ktl) {
        const _Float16* wk = wnet + (((size_t)(kt0 + ktl) * HID) << 5);
        f16x8 bw[8];
#pragma unroll
        for (int rf = 0; rf < 8; ++rf)
          bw[rf] = *(const f16x8*)(wk + ((hid0 + (rf << 4) + l15) << 5) + (l4 << 3));
#pragma unroll
        for (int nf = 0; nf < 2; ++nf) {
          int b = (nf << 4) + l15;
          f16x8 bx;
#pragma unroll
          for (int h = 0; h < 2; ++h) {
            int s = ((l4 << 1) + h) ^ (b & 7);
            f32x4 v = *(const f32x4*)(xl + (b << 9) + (ktl << 7) + (s << 4));
            bx[h * 4 + 0] = (_Float16)v[0];
            bx[h * 4 + 1] = (_Float16)v[1];
            bx[h * 4 + 2] = (_Float16)v[2];
            bx[h * 4 + 3] = (_Float16)v[3];
          }
#pragma unroll
          for (int rf = 0; rf < 8; ++rf)
            acc[rf][nf] = __builtin_amdgcn_mfma_f32_16x16x32_f16(bw[rf], bx, acc[rf][nf], 0, 0, 0);
        }
      }
    };

    // ---- chunk pipeline: compute first, stage-next LAST (vmcnt-FIFO clean) ----
    stage_chunk(xb, bufA);
    __syncthreads();
    compute_chunk(bufA, 0);  stage_chunk(xb + 128, bufB); __syncthreads();
    compute_chunk(bufB, 4);  stage_chunk(xb + 256, bufA); __syncthreads();
    compute_chunk(bufA, 8);  stage_chunk(xb + 384, bufB); __syncthreads();
    compute_chunk(bufB, 12); stage_chunk(xb + 512, bufA); __syncthreads();
    compute_chunk(bufA, 16); stage_chunk(xb + 640, bufB); __syncthreads();
    compute_chunk(bufB, 20); stage_tail();                __syncthreads();
    // tail K-tile (kt 24) from bufA, row stride 128B
    {
      const _Float16* wk = wnet + (((size_t)24 * HID) << 5);
      f16x8 bw[8];
#pragma unroll
      for (int rf = 0; rf < 8; ++rf)
        bw[rf] = *(const f16x8*)(wk + ((hid0 + (rf << 4) + l15) << 5) + (l4 << 3));
#pragma unroll
      for (int nf = 0; nf < 2; ++nf) {
        int b = (nf << 4) + l15;
        f16x8 bx;
#pragma unroll
        for (int h = 0; h < 2; ++h) {
          int s = ((l4 << 1) + h) ^ (b & 7);
          f32x4 v = *(const f32x4*)(bufA + (b << 7) + (s << 4));
          bx[h * 4 + 0] = (_Float16)v[0];
          bx[h * 4 + 1] = (_Float16)v[1];
          bx[h * 4 + 2] = (_Float16)v[2];
          bx[h * 4 + 3] = (_Float16)v[3];
        }
#pragma unroll
        for (int rf = 0; rf < 8; ++rf)
          acc[rf][nf] = __builtin_amdgcn_mfma_f32_16x16x32_f16(bw[rf], bx, acc[rf][nf], 0, 0, 0);
      }
    }
    __syncthreads();   // x fully consumed; bufA/bufB become h

    // ---- publish h: bias+relu+cvt; rows 0..15 -> bufA, 16..31 -> bufB ----
    // lane holds h[hid = hid0+rf*16+l4*4+j][batch = nf*16+l15]
#pragma unroll
    for (int rf = 0; rf < 8; ++rf) {
      f32x4 b1v = *(const f32x4*)(b1 + hid0 + (rf << 4) + (l4 << 2));
#pragma unroll
      for (int nf = 0; nf < 2; ++nf) {
        f16x4 hv;
#pragma unroll
        for (int j = 0; j < 4; ++j)
          hv[j] = (_Float16)fmaxf(acc[rf][nf][j] + b1v[j], 0.f);
        int b  = (nf << 4) + l15;
        int hl = hid0 + (rf << 4) + (l4 << 2);
        int sp = (hl >> 3) ^ (b & 7);
        char* hb = nf ? bufB : bufA;
        *(f16x4*)(hb + ((b & 15) << 10) + (sp << 4) + ((hl & 4) << 1)) = hv;
      }
    }
    __syncthreads();

    // ---- GEMM2 (waves 0,1): logits^T(16x16) per wave over k=512 ----
    if (wid < 2) {
      f32x4 l2 = {0.f, 0.f, 0.f, 0.f};
      const _Float16* w2n = wsW2 + (((net << 4) + l15) << 9);  // A row = logit = l15
      int b = (wid << 4) + l15;                                // B col = batch row
      const char* hb = wid ? bufB : bufA;
#pragma unroll
      for (int kk = 0; kk < 16; ++kk) {
        f16x8 aw = *(const f16x8*)(w2n + (kk << 5) + (l4 << 3));
        int sp = ((kk << 2) + l4) ^ (b & 7);
        f16x8 bh = *(const f16x8*)(hb + ((b & 15) << 10) + (sp << 4));
        l2 = __builtin_amdgcn_mfma_f32_16x16x32_f16(aw, bh, l2, 0, 0, 0);
      }
      // softmax: lane holds logits cls0..cls0+3 of batch row b
      int cls0 = l4 << 2;
      float lg[4];
#pragma unroll
      for (int j = 0; j < 4; ++j) {
        int c = cls0 + j;
        lg[j] = (c < 10) ? (l2[j] + b2[c]) : -1e30f;
      }
      float mx = fmaxf(fmaxf(lg[0], lg[1]), fmaxf(lg[2], lg[3]));
      mx = fmaxf(mx, __shfl_xor(mx, 16));
      mx = fmaxf(mx, __shfl_xor(mx, 32));
      float ev[4], sum = 0.f;
#pragma unroll
      for (int j = 0; j < 4; ++j) {
        ev[j] = (cls0 + j < 10) ? __expf(lg[j] - mx) : 0.f;
        sum += ev[j];
      }
      sum += __shfl_xor(sum, 16);
      sum += __shfl_xor(sum, 32);
      float inv = 1.f / sum;
#pragma unroll
      for (int j = 0; j < 4; ++j) {
        int c = cls0 + j;
        if (c < 10) pbuf[net][b * 11 + c] = ev[j] * inv;
      }
    }
    __syncthreads();   // pbuf visible; bufs free for next net
  } // net

  // ---- out[n][s] = sum_{a+c=s} p0[n][a] * p1[n][c] ----
  float* outb = (float*)bufA;
  {
    int r  = t & 31;
    int sq = t >> 5;                  // 8 squads x 3 s-values (covers 0..23)
#pragma unroll
    for (int si = 0; si < 3; ++si) {
      int s = sq * 3 + si;
      if (s < 19) {
        int alo = (s > 9) ? (s - 9) : 0;
        int ahi = (s < 9) ? s : 9;
        float a = 0.f;
        for (int aa = alo; aa <= ahi; ++aa)
          a += pbuf[0][r * 11 + aa] * pbuf[1][r * 11 + (s - aa)];
        outb[r * 19 + s] = a;
      }
    }
  }
  __syncthreads();
  {
    float* og = out + (size_t)row0 * 19;
    for (int i = t; i < BM * 19; i += 256) og[i] = outb[i];
  }
}

extern "C" void kernel_launch(void* const* d_in, const int* in_sizes, int n_in,
                              void* d_out, int out_size, void* d_ws, size_t ws_size,
                              hipStream_t stream) {
  (void)in_sizes; (void)n_in; (void)out_size; (void)ws_size;
  const float* x    = (const float*)d_in[0];
  const float* W1_0 = (const float*)d_in[1];
  const float* b1_0 = (const float*)d_in[2];
  const float* W2_0 = (const float*)d_in[3];
  const float* b2_0 = (const float*)d_in[4];
  const float* W1_1 = (const float*)d_in[5];
  const float* b1_1 = (const float*)d_in[6];
  const float* W2_1 = (const float*)d_in[7];
  const float* b2_1 = (const float*)d_in[8];
  float* out = (float*)d_out;

  _Float16* wsB  = (_Float16*)d_ws;                 // 2*25*512*32 f16 = 1.6 MB
  _Float16* wsW2 = wsB + 2 * 25 * HID * 32;         // 2*16*512 f16 = 32 KB

  hipLaunchKernelGGL(prep_w1_kernel, dim3(3200), dim3(256), 0, stream, W1_0, W1_1, wsB);
  hipLaunchKernelGGL(prep_w2_kernel, dim3(64), dim3(256), 0, stream, W2_0, W2_1, wsW2);
  hipLaunchKernelGGL(fused_mlp_kernel, dim3(BATCH / BM), dim3(256), 0, stream,
                     x, b1_0, b2_0, b1_1, b2_1, wsB, wsW2, out);
}

// Round 8
// 324.587 us; speedup vs baseline: 1.0458x; 1.0458x over previous
//
#include <hip/hip_runtime.h>
#include <hip/hip_fp16.h>

#define BATCH 65536
#define KDIM  784
#define HID   512
#define BM    32

typedef float    f32x4 __attribute__((ext_vector_type(4)));
typedef _Float16 f16x8 __attribute__((ext_vector_type(8)));
typedef _Float16 f16x4 __attribute__((ext_vector_type(4)));

// W1 (784x512 fp32) -> ws: fp16 in exact A-fragment order [net][kt][hid][32],
// zero-padded to k=800. Consumed global(L2)->reg.
__global__ void prep_w1_kernel(const float* __restrict__ W1_0,
                               const float* __restrict__ W1_1,
                               _Float16* __restrict__ wsB) {
  int i = blockIdx.x * 256 + threadIdx.x;       // [0, 2*800*512)
  if (i >= 2 * 800 * 512) return;
  int net = i / (800 * 512);
  int rem = i - net * (800 * 512);
  int k = rem >> 9;        // 0..799
  int hid = rem & 511;
  const float* W = net ? W1_1 : W1_0;
  float v = (k < KDIM) ? W[k * 512 + hid] : 0.f;
  int kt = k >> 5, kk = k & 31;
  wsB[(((size_t)(net * 25 + kt) * HID + hid) << 5) + kk] = (_Float16)v;
}

// W2 (512x10 fp32) -> ws: fp16 W2^T padded to 16 rows, [net][16][512], linear.
__global__ void prep_w2_kernel(const float* __restrict__ W2_0,
                               const float* __restrict__ W2_1,
                               _Float16* __restrict__ wsW2) {
  int i = blockIdx.x * 256 + threadIdx.x;       // [0, 2*16*512)
  if (i >= 2 * 16 * 512) return;
  int net = i >> 13;
  int rem = i & 8191;
  int li = rem >> 9;       // logit row 0..15
  int k = rem & 511;
  const float* W = net ? W2_1 : W2_0;
  wsW2[i] = (_Float16)((li < 10) ? W[k * 10 + li] : 0.f);
}

__launch_bounds__(256, 3)
__global__ void fused_mlp_kernel(const float* __restrict__ x,
                                 const float* __restrict__ b1_0,
                                 const float* __restrict__ b2_0,
                                 const float* __restrict__ b1_1,
                                 const float* __restrict__ b2_1,
                                 const _Float16* __restrict__ wsB,
                                 const _Float16* __restrict__ wsW2,
                                 float* __restrict__ out) {
  // region: x double-buffer bufA/bufB (2 x 8KB fp16, 32 rows x 256B, XOR-swizzled
  // 16B slots) during GEMM1; then h[32][1024B f16]; then outb.
  __shared__ __attribute__((aligned(16))) char region[32768];
  __shared__ float pbuf[2][BM * 11];

  char* bufA = region;
  char* bufB = region + 8192;

  const int t    = threadIdx.x;
  const int lane = t & 63;
  const int wid  = t >> 6;            // 0..3
  const int l15  = lane & 15;
  const int l4   = lane >> 4;
  const int hid0 = wid << 7;          // wave owns hid [hid0, hid0+128)
  const int row0 = blockIdx.x * BM;

  // stage geometry (big chunks): thread t -> rows {srow, srow+16}, slot ss
  const int srow = t >> 4;            // 0..15
  const int ss   = t & 15;
  const int sg   = ss ^ (srow & 7);   // logical 8-f16 group within chunk
  // tail chunk geometry: one 16B slot per thread
  const int trow = t >> 3;            // 0..31
  const int ts   = t & 7;
  const int tg   = ts ^ (trow & 7);

  for (int net = 0; net < 2; ++net) {
    const float* xb = x + (size_t)net * BATCH * KDIM + (size_t)row0 * KDIM;
    const _Float16* wnet = wsB + (size_t)net * 25 * HID * 32;
    const float* b1 = net ? b1_1 : b1_0;
    const float* b2 = net ? b2_1 : b2_0;

    f32x4 acc[8][2];
#pragma unroll
    for (int rf = 0; rf < 8; ++rf)
#pragma unroll
      for (int nf = 0; nf < 2; ++nf) acc[rf][nf] = (f32x4){0.f, 0.f, 0.f, 0.f};

    f32x4 xr0, xr1, xr2, xr3;         // in-flight stage data (16 VGPR)

    // issue plain vector loads for chunk c (k = c*128 .. +127): 2 rows x 32B
    auto load_chunk = [&](int c) {
      const float* src = xb + (c << 7) + (sg << 3);
      xr0 = *(const f32x4*)(src + (size_t)srow * KDIM);
      xr1 = *(const f32x4*)(src + (size_t)srow * KDIM + 4);
      xr2 = *(const f32x4*)(src + (size_t)(srow + 16) * KDIM);
      xr3 = *(const f32x4*)(src + (size_t)(srow + 16) * KDIM + 4);
    };
    auto load_tail = [&]() {          // kt24: k 768..783 real, rest zero
      if (tg < 2) {
        const float* src = xb + 768 + (tg << 3);
        xr0 = *(const f32x4*)(src + (size_t)trow * KDIM);
        xr1 = *(const f32x4*)(src + (size_t)trow * KDIM + 4);
      } else {
        xr0 = (f32x4){0.f, 0.f, 0.f, 0.f};
        xr1 = (f32x4){0.f, 0.f, 0.f, 0.f};
      }
    };
    auto cvt8 = [](f32x4 a, f32x4 b) {
      f16x8 r;
      r[0] = (_Float16)a[0]; r[1] = (_Float16)a[1];
      r[2] = (_Float16)a[2]; r[3] = (_Float16)a[3];
      r[4] = (_Float16)b[0]; r[5] = (_Float16)b[1];
      r[6] = (_Float16)b[2]; r[7] = (_Float16)b[3];
      return r;
    };
    auto write_chunk = [&](char* buf) {
      *(f16x8*)(buf + srow * 256 + (ss << 4)) = cvt8(xr0, xr1);
      *(f16x8*)(buf + (srow + 16) * 256 + (ss << 4)) = cvt8(xr2, xr3);
    };
    auto write_tail = [&]() {
      *(f16x8*)(bufA + trow * 128 + (ts << 4)) = cvt8(xr0, xr1);
    };
    // 4 K-tiles from an 8KB chunk (W1 frags L2->reg; x f16 direct from LDS)
    auto compute4 = [&](const char* xl, int kt0) {
#pragma unroll 2
      for (int ktl = 0; ktl < 4; ++ktl) {
        const _Float16* wk = wnet + (((size_t)(kt0 + ktl) * HID) << 5);
        f16x8 bw[8];
#pragma unroll
        for (int rf = 0; rf < 8; ++rf)
          bw[rf] = *(const f16x8*)(wk + ((hid0 + (rf << 4) + l15) << 5) + (l4 << 3));
#pragma unroll
        for (int nf = 0; nf < 2; ++nf) {
          int b = (nf << 4) + l15;
          int s = ((ktl << 2) + l4) ^ (b & 7);
          f16x8 bx = *(const f16x8*)(xl + b * 256 + (s << 4));
#pragma unroll
          for (int rf = 0; rf < 8; ++rf)
            acc[rf][nf] = __builtin_amdgcn_mfma_f32_16x16x32_f16(bw[rf], bx, acc[rf][nf], 0, 0, 0);
        }
      }
    };
    auto compute_tail = [&]() {       // kt 24 from bufA (32 rows x 128B)
      const _Float16* wk = wnet + (((size_t)24 * HID) << 5);
      f16x8 bw[8];
#pragma unroll
      for (int rf = 0; rf < 8; ++rf)
        bw[rf] = *(const f16x8*)(wk + ((hid0 + (rf << 4) + l15) << 5) + (l4 << 3));
#pragma unroll
      for (int nf = 0; nf < 2; ++nf) {
        int b = (nf << 4) + l15;
        int s = l4 ^ (b & 7);
        f16x8 bx = *(const f16x8*)(bufA + b * 128 + (s << 4));
#pragma unroll
        for (int rf = 0; rf < 8; ++rf)
          acc[rf][nf] = __builtin_amdgcn_mfma_f32_16x16x32_f16(bw[rf], bx, acc[rf][nf], 0, 0, 0);
      }
    };

    // ---- chunk pipeline: loads(c+1) first (prefetch), ds_write after compute,
    //      one barrier per chunk ----
    load_chunk(0); write_chunk(bufA); __syncthreads();
    load_chunk(1); compute4(bufA, 0);  write_chunk(bufB); __syncthreads();
    load_chunk(2); compute4(bufB, 4);  write_chunk(bufA); __syncthreads();
    load_chunk(3); compute4(bufA, 8);  write_chunk(bufB); __syncthreads();
    load_chunk(4); compute4(bufB, 12); write_chunk(bufA); __syncthreads();
    load_chunk(5); compute4(bufA, 16); write_chunk(bufB); __syncthreads();
    load_tail();   compute4(bufB, 20); write_tail();      __syncthreads();
    compute_tail();
    __syncthreads();   // x fully consumed; region becomes h

    // ---- publish h: bias+relu+cvt; h[b] at region + b*1024, swizzled slots ----
    // lane holds h[hid = hid0+rf*16+l4*4+j][batch = nf*16+l15]
#pragma unroll
    for (int rf = 0; rf < 8; ++rf) {
      f32x4 b1v = *(const f32x4*)(b1 + hid0 + (rf << 4) + (l4 << 2));
#pragma unroll
      for (int nf = 0; nf < 2; ++nf) {
        f16x4 hv;
#pragma unroll
        for (int j = 0; j < 4; ++j)
          hv[j] = (_Float16)fmaxf(acc[rf][nf][j] + b1v[j], 0.f);
        int b  = (nf << 4) + l15;
        int hl = hid0 + (rf << 4) + (l4 << 2);
        int sp = (hl >> 3) ^ (b & 7);
        *(f16x4*)(region + (b << 10) + (sp << 4) + ((hl & 4) << 1)) = hv;
      }
    }
    __syncthreads();

    // ---- GEMM2 (waves 0,1): logits^T(16x16) per wave over k=512 ----
    if (wid < 2) {
      f32x4 l2 = {0.f, 0.f, 0.f, 0.f};
      const _Float16* w2n = wsW2 + (((net << 4) + l15) << 9);  // A row = logit = l15
      int b = (wid << 4) + l15;                                // B col = batch row
#pragma unroll
      for (int kk = 0; kk < 16; ++kk) {
        f16x8 aw = *(const f16x8*)(w2n + (kk << 5) + (l4 << 3));
        int sp = ((kk << 2) + l4) ^ (b & 7);
        f16x8 bh = *(const f16x8*)(region + (b << 10) + (sp << 4));
        l2 = __builtin_amdgcn_mfma_f32_16x16x32_f16(aw, bh, l2, 0, 0, 0);
      }
      // softmax: lane holds logits cls0..cls0+3 of batch row b
      int cls0 = l4 << 2;
      float lg[4];
#pragma unroll
      for (int j = 0; j < 4; ++j) {
        int c = cls0 + j;
        lg[j] = (c < 10) ? (l2[j] + b2[c]) : -1e30f;
      }
      float mx = fmaxf(fmaxf(lg[0], lg[1]), fmaxf(lg[2], lg[3]));
      mx = fmaxf(mx, __shfl_xor(mx, 16));
      mx = fmaxf(mx, __shfl_xor(mx, 32));
      float ev[4], sum = 0.f;
#pragma unroll
      for (int j = 0; j < 4; ++j) {
        ev[j] = (cls0 + j < 10) ? __expf(lg[j] - mx) : 0.f;
        sum += ev[j];
      }
      sum += __shfl_xor(sum, 16);
      sum += __shfl_xor(sum, 32);
      float inv = 1.f / sum;
#pragma unroll
      for (int j = 0; j < 4; ++j) {
        int c = cls0 + j;
        if (c < 10) pbuf[net][b * 11 + c] = ev[j] * inv;
      }
    }
    __syncthreads();   // pbuf visible; region free for next net
  } // net

  // ---- out[n][s] = sum_{a+c=s} p0[n][a] * p1[n][c] ----
  float* outb = (float*)region;
  {
    int r  = t & 31;
    int sq = t >> 5;                  // 8 squads x 3 s-values (covers 0..23)
#pragma unroll
    for (int si = 0; si < 3; ++si) {
      int s = sq * 3 + si;
      if (s < 19) {
        int alo = (s > 9) ? (s - 9) : 0;
        int ahi = (s < 9) ? s : 9;
        float a = 0.f;
        for (int aa = alo; aa <= ahi; ++aa)
          a += pbuf[0][r * 11 + aa] * pbuf[1][r * 11 + (s - aa)];
        outb[r * 19 + s] = a;
      }
    }
  }
  __syncthreads();
  {
    float* og = out + (size_t)row0 * 19;
    for (int i = t; i < BM * 19; i += 256) og[i] = outb[i];
  }
}

extern "C" void kernel_launch(void* const* d_in, const int* in_sizes, int n_in,
                              void* d_out, int out_size, void* d_ws, size_t ws_size,
                              hipStream_t stream) {
  (void)in_sizes; (void)n_in; (void)out_size; (void)ws_size;
  const float* x    = (const float*)d_in[0];
  const float* W1_0 = (const float*)d_in[1];
  const float* b1_0 = (const float*)d_in[2];
  const float* W2_0 = (const float*)d_in[3];
  const float* b2_0 = (const float*)d_in[4];
  const float* W1_1 = (const float*)d_in[5];
  const float* b1_1 = (const float*)d_in[6];
  const float* W2_1 = (const float*)d_in[7];
  const float* b2_1 = (const float*)d_in[8];
  float* out = (float*)d_out;

  _Float16* wsB  = (_Float16*)d_ws;                 // 2*25*512*32 f16 = 1.6 MB
  _Float16* wsW2 = wsB + 2 * 25 * HID * 32;         // 2*16*512 f16 = 32 KB

  hipLaunchKernelGGL(prep_w1_kernel, dim3(3200), dim3(256), 0, stream, W1_0, W1_1, wsB);
  hipLaunchKernelGGL(prep_w2_kernel, dim3(64), dim3(256), 0, stream, W2_0, W2_1, wsW2);
  hipLaunchKernelGGL(fused_mlp_kernel, dim3(BATCH / BM), dim3(256), 0, stream,
                     x, b1_0, b2_0, b1_1, b2_1, wsB, wsW2, out);
}

// Round 9
// 236.738 us; speedup vs baseline: 1.4339x; 1.3711x over previous
//
#include <hip/hip_runtime.h>
#include <hip/hip_fp16.h>

#define BATCH 65536
#define KDIM  784
#define HID   512
#define BM    64

typedef float    f32x4 __attribute__((ext_vector_type(4)));
typedef _Float16 f16x8 __attribute__((ext_vector_type(8)));
typedef _Float16 f16x4 __attribute__((ext_vector_type(4)));

// W1 (784x512 fp32) -> ws: fp16 in exact A-fragment order [net][kt][hid][32],
// zero-padded to k=800. Consumed global(L2)->reg.
__global__ void prep_w1_kernel(const float* __restrict__ W1_0,
                               const float* __restrict__ W1_1,
                               _Float16* __restrict__ wsB) {
  int i = blockIdx.x * 256 + threadIdx.x;       // [0, 2*800*512)
  if (i >= 2 * 800 * 512) return;
  int net = i / (800 * 512);
  int rem = i - net * (800 * 512);
  int k = rem >> 9;        // 0..799
  int hid = rem & 511;
  const float* W = net ? W1_1 : W1_0;
  float v = (k < KDIM) ? W[k * 512 + hid] : 0.f;
  int kt = k >> 5, kk = k & 31;
  wsB[(((size_t)(net * 25 + kt) * HID + hid) << 5) + kk] = (_Float16)v;
}

// W2 (512x10 fp32) -> ws: fp16 W2^T padded to 16 rows, [net][16][512], linear.
__global__ void prep_w2_kernel(const float* __restrict__ W2_0,
                               const float* __restrict__ W2_1,
                               _Float16* __restrict__ wsW2) {
  int i = blockIdx.x * 256 + threadIdx.x;       // [0, 2*16*512)
  if (i >= 2 * 16 * 512) return;
  int net = i >> 13;
  int rem = i & 8191;
  int li = rem >> 9;       // logit row 0..15
  int k = rem & 511;
  const float* W = net ? W2_1 : W2_0;
  wsW2[i] = (_Float16)((li < 10) ? W[k * 10 + li] : 0.f);
}

__launch_bounds__(512, 4)
__global__ void fused_mlp_kernel(const float* __restrict__ x,
                                 const float* __restrict__ b1_0,
                                 const float* __restrict__ b2_0,
                                 const float* __restrict__ b1_1,
                                 const float* __restrict__ b2_1,
                                 const _Float16* __restrict__ wsB,
                                 const _Float16* __restrict__ wsW2,
                                 float* __restrict__ out) {
  // bufA/bufB: x k=128 chunks (64 rows x 256B fp16, XOR-swizzled 16B slots).
  // After GEMM1, bufA is reused for h half-tiles (32 rows x 1KB) and then outb.
  __shared__ __attribute__((aligned(16))) char bufA[32768];
  __shared__ __attribute__((aligned(16))) char bufB[32768];
  __shared__ float pbuf[2][BM * 11];

  const int t    = threadIdx.x;
  const int lane = t & 63;
  const int wid  = t >> 6;            // 0..7
  const int l15  = lane & 15;
  const int l4   = lane >> 4;
  const int hid0 = wid << 6;          // wave owns hid [hid0, hid0+64)
  const int row0 = blockIdx.x * BM;

  // stage geometry: thread t -> row r, 64B contiguous at slot-pair {2q, 2q+1}
  const int sr = t >> 3;              // 0..63
  const int sq = t & 7;
  // tail geometry (first 256 threads): row tr, logical slot tsl (k 768+8*tsl)
  const int tr  = t >> 2;
  const int tsl = t & 3;

  for (int net = 0; net < 2; ++net) {
    const float* xb = x + (size_t)net * BATCH * KDIM + (size_t)row0 * KDIM;
    const _Float16* wnet = wsB + (size_t)net * 25 * HID * 32;
    const float* b1 = net ? b1_1 : b1_0;
    const float* b2 = net ? b2_1 : b2_0;

    f32x4 acc[4][4];
#pragma unroll
    for (int rf = 0; rf < 4; ++rf)
#pragma unroll
      for (int nf = 0; nf < 4; ++nf) acc[rf][nf] = (f32x4){0.f, 0.f, 0.f, 0.f};

    f32x4 xr0, xr1, xr2, xr3;         // in-flight stage data (16 VGPR)

    // issue loads for chunk c (k = c*128..+127): 64B contiguous per thread
    auto load_chunk = [&](int c) {
      const float* src = xb + (size_t)sr * KDIM + (c << 7) + (sq << 4);
      xr0 = *(const f32x4*)(src);
      xr1 = *(const f32x4*)(src + 4);
      xr2 = *(const f32x4*)(src + 8);
      xr3 = *(const f32x4*)(src + 12);
    };
    auto load_tail = [&]() {          // kt24: k 768..783 real, 784..799 zero
      if (t < 256) {
        if (tsl < 2) {
          const float* src = xb + (size_t)tr * KDIM + 768 + (tsl << 3);
          xr0 = *(const f32x4*)(src);
          xr1 = *(const f32x4*)(src + 4);
        } else {
          xr0 = (f32x4){0.f, 0.f, 0.f, 0.f};
          xr1 = (f32x4){0.f, 0.f, 0.f, 0.f};
        }
      }
    };
    auto cvt8 = [](f32x4 a, f32x4 b) {
      f16x8 r;
      r[0] = (_Float16)a[0]; r[1] = (_Float16)a[1];
      r[2] = (_Float16)a[2]; r[3] = (_Float16)a[3];
      r[4] = (_Float16)b[0]; r[5] = (_Float16)b[1];
      r[6] = (_Float16)b[2]; r[7] = (_Float16)b[3];
      return r;
    };
    // logical slot s (8 f16 = k [s*8, s*8+8)) lives at physical slot s^(r&7)
    auto write_chunk = [&](char* buf) {
      int s0 = sq << 1;
      *(f16x8*)(buf + sr * 256 + (((s0) ^ (sr & 7)) << 4)) = cvt8(xr0, xr1);
      *(f16x8*)(buf + sr * 256 + (((s0 + 1) ^ (sr & 7)) << 4)) = cvt8(xr2, xr3);
    };
    auto write_tail = [&]() {         // 64 rows x 128B at head of bufA
      if (t < 256)
        *(f16x8*)(bufA + tr * 128 + ((tsl ^ (tr & 7)) << 4)) = cvt8(xr0, xr1);
    };
    // 4 K-tiles from a 32KB chunk (W1 frags L2->reg; x f16 direct from LDS)
    auto compute4 = [&](const char* xl, int kt0) {
#pragma unroll 2
      for (int ktl = 0; ktl < 4; ++ktl) {
        const _Float16* wk = wnet + (((size_t)(kt0 + ktl) * HID) << 5);
        f16x8 bw[4];
#pragma unroll
        for (int rf = 0; rf < 4; ++rf)
          bw[rf] = *(const f16x8*)(wk + ((hid0 + (rf << 4) + l15) << 5) + (l4 << 3));
#pragma unroll
        for (int nf = 0; nf < 4; ++nf) {
          int b = (nf << 4) + l15;
          int g = (ktl << 2) + l4;
          f16x8 bx = *(const f16x8*)(xl + b * 256 + ((g ^ (b & 7)) << 4));
#pragma unroll
          for (int rf = 0; rf < 4; ++rf)
            acc[rf][nf] = __builtin_amdgcn_mfma_f32_16x16x32_f16(bw[rf], bx, acc[rf][nf], 0, 0, 0);
        }
      }
    };
    auto compute_tail = [&]() {       // kt 24 from bufA (64 rows x 128B)
      const _Float16* wk = wnet + (((size_t)24 * HID) << 5);
      f16x8 bw[4];
#pragma unroll
      for (int rf = 0; rf < 4; ++rf)
        bw[rf] = *(const f16x8*)(wk + ((hid0 + (rf << 4) + l15) << 5) + (l4 << 3));
#pragma unroll
      for (int nf = 0; nf < 4; ++nf) {
        int b = (nf << 4) + l15;
        f16x8 bx = *(const f16x8*)(bufA + b * 128 + ((l4 ^ (b & 7)) << 4));
#pragma unroll
        for (int rf = 0; rf < 4; ++rf)
          acc[rf][nf] = __builtin_amdgcn_mfma_f32_16x16x32_f16(bw[rf], bx, acc[rf][nf], 0, 0, 0);
      }
    };

    // ---- chunk pipeline: loads(c+1) first, ds_write after compute(c) ----
    load_chunk(0); write_chunk(bufA); __syncthreads();
    load_chunk(1); compute4(bufA, 0);  write_chunk(bufB); __syncthreads();
    load_chunk(2); compute4(bufB, 4);  write_chunk(bufA); __syncthreads();
    load_chunk(3); compute4(bufA, 8);  write_chunk(bufB); __syncthreads();
    load_chunk(4); compute4(bufB, 12); write_chunk(bufA); __syncthreads();
    load_chunk(5); compute4(bufA, 16); write_chunk(bufB); __syncthreads();
    load_tail();   compute4(bufB, 20); write_tail();      __syncthreads();
    compute_tail();
    __syncthreads();   // x fully consumed; bufA becomes h half-buffer

    // ---- h publish + GEMM2 + softmax, in two 32-row halves ----
#pragma unroll
    for (int hf = 0; hf < 2; ++hf) {
      // publish batch rows hf*32..hf*32+31 (nf = 2hf, 2hf+1)
#pragma unroll
      for (int rf = 0; rf < 4; ++rf) {
        f32x4 b1v = *(const f32x4*)(b1 + hid0 + (rf << 4) + (l4 << 2));
#pragma unroll
        for (int nfi = 0; nfi < 2; ++nfi) {
          int nf = (hf << 1) + nfi;
          f16x4 hv;
#pragma unroll
          for (int j = 0; j < 4; ++j)
            hv[j] = (_Float16)fmaxf(acc[rf][nf][j] + b1v[j], 0.f);
          int bl = (nfi << 4) + l15;            // local row 0..31
          int hl = hid0 + (rf << 4) + (l4 << 2);
          int sp = (hl >> 3) ^ (bl & 7);
          *(f16x4*)(bufA + (bl << 10) + (sp << 4) + ((hl & 4) << 1)) = hv;
        }
      }
      __syncthreads();

      // GEMM2 on this half: waves 0,1 each take 16 rows, k=512
      if (wid < 2) {
        f32x4 l2 = {0.f, 0.f, 0.f, 0.f};
        const _Float16* w2n = wsW2 + (((net << 4) + l15) << 9);  // A row = logit
        int bl = (wid << 4) + l15;                               // local batch row
#pragma unroll
        for (int kk = 0; kk < 16; ++kk) {
          f16x8 aw = *(const f16x8*)(w2n + (kk << 5) + (l4 << 3));
          int s = (kk << 2) + l4;
          f16x8 bh = *(const f16x8*)(bufA + (bl << 10) + ((s ^ (bl & 7)) << 4));
          l2 = __builtin_amdgcn_mfma_f32_16x16x32_f16(aw, bh, l2, 0, 0, 0);
        }
        // softmax: lane holds logits cls0..cls0+3 of local row bl
        int cls0 = l4 << 2;
        float lg[4];
#pragma unroll
        for (int j = 0; j < 4; ++j) {
          int c = cls0 + j;
          lg[j] = (c < 10) ? (l2[j] + b2[c]) : -1e30f;
        }
        float mx = fmaxf(fmaxf(lg[0], lg[1]), fmaxf(lg[2], lg[3]));
        mx = fmaxf(mx, __shfl_xor(mx, 16));
        mx = fmaxf(mx, __shfl_xor(mx, 32));
        float ev[4], sum = 0.f;
#pragma unroll
        for (int j = 0; j < 4; ++j) {
          ev[j] = (cls0 + j < 10) ? __expf(lg[j] - mx) : 0.f;
          sum += ev[j];
        }
        sum += __shfl_xor(sum, 16);
        sum += __shfl_xor(sum, 32);
        float inv = 1.f / sum;
        int bg = (hf << 5) + bl;                // global batch row in block
#pragma unroll
        for (int j = 0; j < 4; ++j) {
          int c = cls0 + j;
          if (c < 10) pbuf[net][bg * 11 + c] = ev[j] * inv;
        }
      }
      __syncthreads();   // half consumed; bufA free for next half / next net
    }
  } // net

  // ---- out[n][s] = sum_{a+c=s} p0[n][a] * p1[n][c] ----
  float* outb = (float*)bufA;
  {
    int r  = t & 63;
    int sg = t >> 6;                  // 8 squads x 3 s-values (covers 0..23)
#pragma unroll
    for (int si = 0; si < 3; ++si) {
      int s = sg * 3 + si;
      if (s < 19) {
        int alo = (s > 9) ? (s - 9) : 0;
        int ahi = (s < 9) ? s : 9;
        float a = 0.f;
        for (int aa = alo; aa <= ahi; ++aa)
          a += pbuf[0][r * 11 + aa] * pbuf[1][r * 11 + (s - aa)];
        outb[r * 19 + s] = a;
      }
    }
  }
  __syncthreads();
  {
    float* og = out + (size_t)row0 * 19;
    for (int i = t; i < BM * 19; i += 512) og[i] = outb[i];
  }
}

extern "C" void kernel_launch(void* const* d_in, const int* in_sizes, int n_in,
                              void* d_out, int out_size, void* d_ws, size_t ws_size,
                              hipStream_t stream) {
  (void)in_sizes; (void)n_in; (void)out_size; (void)ws_size;
  const float* x    = (const float*)d_in[0];
  const float* W1_0 = (const float*)d_in[1];
  const float* b1_0 = (const float*)d_in[2];
  const float* W2_0 = (const float*)d_in[3];
  const float* b2_0 = (const float*)d_in[4];
  const float* W1_1 = (const float*)d_in[5];
  const float* b1_1 = (const float*)d_in[6];
  const float* W2_1 = (const float*)d_in[7];
  const float* b2_1 = (const float*)d_in[8];
  float* out = (float*)d_out;

  _Float16* wsB  = (_Float16*)d_ws;                 // 2*25*512*32 f16 = 1.6 MB
  _Float16* wsW2 = wsB + 2 * 25 * HID * 32;         // 2*16*512 f16 = 32 KB

  hipLaunchKernelGGL(prep_w1_kernel, dim3(3200), dim3(256), 0, stream, W1_0, W1_1, wsB);
  hipLaunchKernelGGL(prep_w2_kernel, dim3(64), dim3(256), 0, stream, W2_0, W2_1, wsW2);
  hipLaunchKernelGGL(fused_mlp_kernel, dim3(BATCH / BM), dim3(512), 0, stream,
                     x, b1_0, b2_0, b1_1, b2_1, wsB, wsW2, out);
}